// Round 4
// baseline (484.738 us; speedup 1.0000x reference)
//
#include <hip/hip_runtime.h>
#include <cstdint>
#include <cstddef>

#define N_NODES 50000
#define N_EDGES 800000
#define DIM_IN  128
#define DIM_OUT 64

#define NB      1024                               // padded bucket count (pow2)
#define BSHIFT  6                                  // 64 nodes per bucket
#define BNODES  64
#define NBK     ((N_NODES + BNODES - 1) / BNODES)  // 782 buckets actually used
#define EB      4096                               // edges per sort tile
#define SORTB   ((N_EDGES + EB - 1) / EB)          // 196 sort tiles

// ---------------------------------------------------------------------------
// A: per-tile histogram over coarse dst-buckets (LDS atomics only).
// M[tile][bucket], coalesced plain stores.
// ---------------------------------------------------------------------------
__global__ __launch_bounds__(256) void kA_hist(const int* __restrict__ ei,
                                               int* __restrict__ M) {
    __shared__ int hcnt[NB];
    const int t = threadIdx.x, blk = blockIdx.x;
    for (int i = t; i < NB; i += 256) hcnt[i] = 0;
    __syncthreads();
    const int base = blk * EB;
#pragma unroll
    for (int it = 0; it < EB / 256; ++it) {
        int e = base + it * 256 + t;
        if (e < N_EDGES) atomicAdd(&hcnt[ei[N_EDGES + e] >> BSHIFT], 1);
    }
    __syncthreads();
    for (int i = t; i < NB; i += 256) M[blk * NB + i] = hcnt[i];
}

// ---------------------------------------------------------------------------
// B1: one block. bucket totals (sum over tiles) -> exclusive bucket starts.
// bstart[NB+1]; bstart[NB] = N_EDGES.
// ---------------------------------------------------------------------------
__global__ __launch_bounds__(NB) void kB1(const int* __restrict__ M,
                                          int* __restrict__ bstart) {
    __shared__ int s[NB];
    const int t = threadIdx.x;
    int sum = 0;
    for (int blk = 0; blk < SORTB; ++blk) sum += M[blk * NB + t];
    s[t] = sum;
    __syncthreads();
    for (int off = 1; off < NB; off <<= 1) {
        int add = (t >= off) ? s[t - off] : 0;
        __syncthreads();
        s[t] += add;
        __syncthreads();
    }
    bstart[t] = s[t] - sum;                 // exclusive
    if (t == NB - 1) bstart[NB] = s[t];     // total
}

// ---------------------------------------------------------------------------
// B2: per-bucket exclusive prefix over tiles -> starts[tile][bucket].
// ---------------------------------------------------------------------------
__global__ __launch_bounds__(256) void kB2(const int* __restrict__ M,
                                           const int* __restrict__ bstart,
                                           int* __restrict__ starts) {
    __shared__ int s[256];
    const int b = blockIdx.x, t = threadIdx.x;
    const int v = (t < SORTB) ? M[t * NB + b] : 0;
    s[t] = v;
    __syncthreads();
    for (int off = 1; off < 256; off <<= 1) {
        int add = (t >= off) ? s[t - off] : 0;
        __syncthreads();
        s[t] += add;
        __syncthreads();
    }
    if (t < SORTB) starts[t * NB + b] = bstart[b] + s[t] - v;
}

// ---------------------------------------------------------------------------
// C: scatter packed (src<<16)|dst into bucket segments. Ranks from LDS
// cursors (LDS atomics); plain write-back global stores (no global atomics).
// ---------------------------------------------------------------------------
__global__ __launch_bounds__(256) void kC_scatter(const int* __restrict__ ei,
                                                  const int* __restrict__ starts,
                                                  unsigned* __restrict__ pairs) {
    __shared__ int cur[NB];
    const int t = threadIdx.x, blk = blockIdx.x;
    for (int i = t; i < NB; i += 256) cur[i] = starts[blk * NB + i];
    __syncthreads();
    const int base = blk * EB;
#pragma unroll
    for (int it = 0; it < EB / 256; ++it) {
        int e = base + it * 256 + t;
        if (e < N_EDGES) {
            unsigned src = (unsigned)ei[e];
            unsigned dst = (unsigned)ei[N_EDGES + e];
            int pos = atomicAdd(&cur[dst >> BSHIFT], 1);
            pairs[pos] = (src << 16) | dst;   // both < 2^16
        }
    }
}

// ---------------------------------------------------------------------------
// D1: per-bucket degree count from bucketed pairs -> dinv = rsqrt(deg+1).
// No global atomics.
// ---------------------------------------------------------------------------
__global__ __launch_bounds__(256) void kD1_deg(const unsigned* __restrict__ pairs,
                                               const int* __restrict__ bstart,
                                               float* __restrict__ dinv) {
    __shared__ int cnt[BNODES];
    const int b = blockIdx.x, t = threadIdx.x;
    if (t < BNODES) cnt[t] = 0;
    __syncthreads();
    const int eb = bstart[b], ee = bstart[b + 1];
    for (int i = eb + t; i < ee; i += 256)
        atomicAdd(&cnt[pairs[i] & (BNODES - 1)], 1);
    __syncthreads();
    if (t < BNODES) {
        int n = (b << BSHIFT) + t;
        if (n < N_NODES) dinv[n] = rsqrtf((float)(cnt[t] + 1));
    }
}

// ---------------------------------------------------------------------------
// GEMM: h_scaled[n,:] = (x[n,:] @ W) * dinv[n]. 16 rows/block, lane = col.
// ---------------------------------------------------------------------------
__global__ __launch_bounds__(256) void k_gemm(const float* __restrict__ x,
                                              const float* __restrict__ W,
                                              const float* __restrict__ dinv,
                                              float* __restrict__ h) {
    __shared__ float Wl[DIM_IN * DIM_OUT];   // 32 KB
    __shared__ float Xl[16 * DIM_IN];        // 8 KB

    const int t = threadIdx.x;
    const int rowBase = blockIdx.x * 16;

    for (int i = t; i < DIM_IN * DIM_OUT; i += 256) Wl[i] = W[i];
    const float* xg = x + (size_t)rowBase * DIM_IN;
    for (int i = t; i < 16 * DIM_IN; i += 256) Xl[i] = xg[i];
    __syncthreads();

    const int lane = t & 63;
    const int r0 = (t >> 6) * 4;

    float acc0 = 0.f, acc1 = 0.f, acc2 = 0.f, acc3 = 0.f;
#pragma unroll 4
    for (int k = 0; k < DIM_IN; k += 4) {
        const float w0 = Wl[(k + 0) * DIM_OUT + lane];
        const float w1 = Wl[(k + 1) * DIM_OUT + lane];
        const float w2 = Wl[(k + 2) * DIM_OUT + lane];
        const float w3 = Wl[(k + 3) * DIM_OUT + lane];
        const float4 a0 = *(const float4*)&Xl[(r0 + 0) * DIM_IN + k];
        const float4 a1 = *(const float4*)&Xl[(r0 + 1) * DIM_IN + k];
        const float4 a2 = *(const float4*)&Xl[(r0 + 2) * DIM_IN + k];
        const float4 a3 = *(const float4*)&Xl[(r0 + 3) * DIM_IN + k];
        acc0 = fmaf(a0.x, w0, acc0); acc0 = fmaf(a0.y, w1, acc0);
        acc0 = fmaf(a0.z, w2, acc0); acc0 = fmaf(a0.w, w3, acc0);
        acc1 = fmaf(a1.x, w0, acc1); acc1 = fmaf(a1.y, w1, acc1);
        acc1 = fmaf(a1.z, w2, acc1); acc1 = fmaf(a1.w, w3, acc1);
        acc2 = fmaf(a2.x, w0, acc2); acc2 = fmaf(a2.y, w1, acc2);
        acc2 = fmaf(a2.z, w2, acc2); acc2 = fmaf(a2.w, w3, acc2);
        acc3 = fmaf(a3.x, w0, acc3); acc3 = fmaf(a3.y, w1, acc3);
        acc3 = fmaf(a3.z, w2, acc3); acc3 = fmaf(a3.w, w3, acc3);
    }

    const int row = rowBase + r0;
    h[(size_t)(row + 0) * DIM_OUT + lane] = acc0 * dinv[row + 0];
    h[(size_t)(row + 1) * DIM_OUT + lane] = acc1 * dinv[row + 1];
    h[(size_t)(row + 2) * DIM_OUT + lane] = acc2 * dinv[row + 2];
    h[(size_t)(row + 3) * DIM_OUT + lane] = acc3 * dinv[row + 3];
}

// ---------------------------------------------------------------------------
// D2: per-bucket aggregation into LDS (ds_add_f32), fused self-loop + bias
// + log_softmax, sequential out writes. 16 waves/block, wave-per-edge.
// ---------------------------------------------------------------------------
__global__ __launch_bounds__(1024) void kD2_agg(const unsigned* __restrict__ pairs,
                                                const int* __restrict__ bstart,
                                                const float* __restrict__ h,
                                                const float* __restrict__ dinv,
                                                const float* __restrict__ bvec,
                                                float* __restrict__ out) {
    __shared__ float acc[BNODES * DIM_OUT];   // 16 KB
    const int t = threadIdx.x, b = blockIdx.x;
    const int w = t >> 6, lane = t & 63;

    for (int i = t; i < BNODES * DIM_OUT; i += 1024) acc[i] = 0.0f;
    const float bias = bvec[lane];
    __syncthreads();

    const int eb = bstart[b], ee = bstart[b + 1];
    int e = eb + w;
    for (; e + 16 < ee; e += 32) {           // 2-way unrolled, stride 16 waves
        const unsigned p0 = pairs[e];
        const unsigned p1 = pairs[e + 16];
        const float v0 = h[(size_t)(p0 >> 16) * DIM_OUT + lane];
        const float v1 = h[(size_t)(p1 >> 16) * DIM_OUT + lane];
        atomicAdd(&acc[(p0 & (BNODES - 1)) * DIM_OUT + lane], v0);
        atomicAdd(&acc[(p1 & (BNODES - 1)) * DIM_OUT + lane], v1);
    }
    if (e < ee) {
        const unsigned p0 = pairs[e];
        const float v0 = h[(size_t)(p0 >> 16) * DIM_OUT + lane];
        atomicAdd(&acc[(p0 & (BNODES - 1)) * DIM_OUT + lane], v0);
    }
    __syncthreads();

    for (int r = w; r < BNODES; r += 16) {
        const int n = (b << BSHIFT) + r;
        if (n >= N_NODES) continue;          // wave-uniform
        float v = acc[r * DIM_OUT + lane] + h[(size_t)n * DIM_OUT + lane];
        v = v * dinv[n] + bias;

        float m = v;
#pragma unroll
        for (int off = 32; off > 0; off >>= 1) m = fmaxf(m, __shfl_xor(m, off));
        float ex = __expf(v - m);
        float s = ex;
#pragma unroll
        for (int off = 32; off > 0; off >>= 1) s += __shfl_xor(s, off);

        out[(size_t)n * DIM_OUT + lane] = v - m - __logf(s);
    }
}

// ---------------------------------------------------------------------------
extern "C" void kernel_launch(void* const* d_in, const int* in_sizes, int n_in,
                              void* d_out, int out_size, void* d_ws, size_t ws_size,
                              hipStream_t stream) {
    const float* x  = (const float*)d_in[0];
    const int*   ei = (const int*)d_in[1];   // [2, E]: row0 = src, row1 = dst
    const float* W  = (const float*)d_in[2];
    const float* b  = (const float*)d_in[3];
    float* out = (float*)d_out;

    // workspace: h 12.8MB | dinv 200KB | pairs 3.2MB | M 0.8MB | starts 0.8MB
    //          | bstart 4.1KB   (total ~17.8 MB)
    char* ws = (char*)d_ws;
    float*    h      = (float*)ws;    ws += (size_t)N_NODES * DIM_OUT * sizeof(float);
    float*    dinv   = (float*)ws;    ws += (size_t)N_NODES * sizeof(float);
    unsigned* pairs  = (unsigned*)ws; ws += (size_t)N_EDGES * sizeof(unsigned);
    int*      M      = (int*)ws;      ws += (size_t)SORTB * NB * sizeof(int);
    int*      starts = (int*)ws;      ws += (size_t)SORTB * NB * sizeof(int);
    int*      bstart = (int*)ws;      ws += (size_t)(NB + 1) * sizeof(int);

    kA_hist   <<<SORTB, 256, 0, stream>>>(ei, M);
    kB1       <<<1, NB, 0, stream>>>(M, bstart);
    kB2       <<<NB, 256, 0, stream>>>(M, bstart, starts);
    kC_scatter<<<SORTB, 256, 0, stream>>>(ei, starts, pairs);
    kD1_deg   <<<NBK, 256, 0, stream>>>(pairs, bstart, dinv);
    k_gemm    <<<N_NODES / 16, 256, 0, stream>>>(x, W, dinv, h);
    kD2_agg   <<<NBK, 1024, 0, stream>>>(pairs, bstart, h, dinv, b, out);
}

// Round 5
// 190.845 us; speedup vs baseline: 2.5400x; 2.5400x over previous
//
#include <hip/hip_runtime.h>
#include <cstdint>
#include <cstddef>

#define N_NODES 50000
#define N_EDGES 800000
#define DIM_IN  128
#define DIM_OUT 64

#define NB      1024                               // padded bucket count (pow2)
#define BSHIFT  6                                  // 64 nodes per bucket
#define BNODES  64
#define NBK     ((N_NODES + BNODES - 1) / BNODES)  // 782 buckets actually used
#define EB      4096                               // edges per sort tile
#define SORTB   ((N_EDGES + EB - 1) / EB)          // 196 sort tiles
#define CAP     3072                               // in-LDS bucket capacity (mean 1024, sd 32)

// ---------------------------------------------------------------------------
// A: per-tile histogram over coarse dst-buckets (scalar LDS int atomics).
// ---------------------------------------------------------------------------
__global__ __launch_bounds__(256) void kA_hist(const int* __restrict__ ei,
                                               int* __restrict__ M) {
    __shared__ int hcnt[NB];
    const int t = threadIdx.x, blk = blockIdx.x;
    for (int i = t; i < NB; i += 256) hcnt[i] = 0;
    __syncthreads();
    const int base = blk * EB;
#pragma unroll
    for (int it = 0; it < EB / 256; ++it) {
        int e = base + it * 256 + t;
        if (e < N_EDGES) atomicAdd(&hcnt[ei[N_EDGES + e] >> BSHIFT], 1);
    }
    __syncthreads();
    for (int i = t; i < NB; i += 256) M[blk * NB + i] = hcnt[i];
}

// ---------------------------------------------------------------------------
// B1: one block. bucket totals (sum over tiles) -> exclusive bucket starts.
// Unroll 8 keeps 8 independent loads in flight (196-deep loop).
// ---------------------------------------------------------------------------
__global__ __launch_bounds__(NB) void kB1(const int* __restrict__ M,
                                          int* __restrict__ bstart) {
    __shared__ int s[NB];
    const int t = threadIdx.x;
    int sum = 0;
#pragma unroll 8
    for (int blk = 0; blk < SORTB; ++blk) sum += M[blk * NB + t];
    s[t] = sum;
    __syncthreads();
    for (int off = 1; off < NB; off <<= 1) {
        int add = (t >= off) ? s[t - off] : 0;
        __syncthreads();
        s[t] += add;
        __syncthreads();
    }
    bstart[t] = s[t] - sum;                 // exclusive
    if (t == NB - 1) bstart[NB] = s[t];     // total (= N_EDGES)
}

// ---------------------------------------------------------------------------
// B2: per-bucket exclusive prefix over tiles -> starts[tile][bucket].
// ---------------------------------------------------------------------------
__global__ __launch_bounds__(256) void kB2(const int* __restrict__ M,
                                           const int* __restrict__ bstart,
                                           int* __restrict__ starts) {
    __shared__ int s[256];
    const int b = blockIdx.x, t = threadIdx.x;
    const int v = (t < SORTB) ? M[t * NB + b] : 0;
    s[t] = v;
    __syncthreads();
    for (int off = 1; off < 256; off <<= 1) {
        int add = (t >= off) ? s[t - off] : 0;
        __syncthreads();
        s[t] += add;
        __syncthreads();
    }
    if (t < SORTB) starts[t * NB + b] = bstart[b] + s[t] - v;
}

// ---------------------------------------------------------------------------
// C: scatter packed (src<<16)|dst into bucket segments. LDS cursor atomics,
// plain write-back global stores. No global atomics.
// ---------------------------------------------------------------------------
__global__ __launch_bounds__(256) void kC_scatter(const int* __restrict__ ei,
                                                  const int* __restrict__ starts,
                                                  unsigned* __restrict__ pairs) {
    __shared__ int cur[NB];
    const int t = threadIdx.x, blk = blockIdx.x;
    for (int i = t; i < NB; i += 256) cur[i] = starts[blk * NB + i];
    __syncthreads();
    const int base = blk * EB;
#pragma unroll
    for (int it = 0; it < EB / 256; ++it) {
        int e = base + it * 256 + t;
        if (e < N_EDGES) {
            unsigned src = (unsigned)ei[e];
            unsigned dst = (unsigned)ei[N_EDGES + e];
            int pos = atomicAdd(&cur[dst >> BSHIFT], 1);
            pairs[pos] = (src << 16) | dst;   // both < 2^16
        }
    }
}

// ---------------------------------------------------------------------------
// D1: per-bucket degree count from bucketed pairs -> dinv = rsqrt(deg+1).
// Needed by k_gemm for pre-scaling. Scalar LDS int atomics only.
// ---------------------------------------------------------------------------
__global__ __launch_bounds__(256) void kD1_deg(const unsigned* __restrict__ pairs,
                                               const int* __restrict__ bstart,
                                               float* __restrict__ dinv) {
    __shared__ int cnt[BNODES];
    const int b = blockIdx.x, t = threadIdx.x;
    if (t < BNODES) cnt[t] = 0;
    __syncthreads();
    const int eb = bstart[b], ee = bstart[b + 1];
    for (int i = eb + t; i < ee; i += 256)
        atomicAdd(&cnt[pairs[i] & (BNODES - 1)], 1);
    __syncthreads();
    if (t < BNODES) {
        int n = (b << BSHIFT) + t;
        if (n < N_NODES) dinv[n] = rsqrtf((float)(cnt[t] + 1));
    }
}

// ---------------------------------------------------------------------------
// GEMM: h_scaled[n,:] = (x[n,:] @ W) * dinv[n]. 16 rows/block, lane = col.
// ---------------------------------------------------------------------------
__global__ __launch_bounds__(256) void k_gemm(const float* __restrict__ x,
                                              const float* __restrict__ W,
                                              const float* __restrict__ dinv,
                                              float* __restrict__ h) {
    __shared__ float Wl[DIM_IN * DIM_OUT];   // 32 KB
    __shared__ float Xl[16 * DIM_IN];        // 8 KB

    const int t = threadIdx.x;
    const int rowBase = blockIdx.x * 16;

    for (int i = t; i < DIM_IN * DIM_OUT; i += 256) Wl[i] = W[i];
    const float* xg = x + (size_t)rowBase * DIM_IN;
    for (int i = t; i < 16 * DIM_IN; i += 256) Xl[i] = xg[i];
    __syncthreads();

    const int lane = t & 63;
    const int r0 = (t >> 6) * 4;

    float acc0 = 0.f, acc1 = 0.f, acc2 = 0.f, acc3 = 0.f;
#pragma unroll 4
    for (int k = 0; k < DIM_IN; k += 4) {
        const float w0 = Wl[(k + 0) * DIM_OUT + lane];
        const float w1 = Wl[(k + 1) * DIM_OUT + lane];
        const float w2 = Wl[(k + 2) * DIM_OUT + lane];
        const float w3 = Wl[(k + 3) * DIM_OUT + lane];
        const float4 a0 = *(const float4*)&Xl[(r0 + 0) * DIM_IN + k];
        const float4 a1 = *(const float4*)&Xl[(r0 + 1) * DIM_IN + k];
        const float4 a2 = *(const float4*)&Xl[(r0 + 2) * DIM_IN + k];
        const float4 a3 = *(const float4*)&Xl[(r0 + 3) * DIM_IN + k];
        acc0 = fmaf(a0.x, w0, acc0); acc0 = fmaf(a0.y, w1, acc0);
        acc0 = fmaf(a0.z, w2, acc0); acc0 = fmaf(a0.w, w3, acc0);
        acc1 = fmaf(a1.x, w0, acc1); acc1 = fmaf(a1.y, w1, acc1);
        acc1 = fmaf(a1.z, w2, acc1); acc1 = fmaf(a1.w, w3, acc1);
        acc2 = fmaf(a2.x, w0, acc2); acc2 = fmaf(a2.y, w1, acc2);
        acc2 = fmaf(a2.z, w2, acc2); acc2 = fmaf(a2.w, w3, acc2);
        acc3 = fmaf(a3.x, w0, acc3); acc3 = fmaf(a3.y, w1, acc3);
        acc3 = fmaf(a3.z, w2, acc3); acc3 = fmaf(a3.w, w3, acc3);
    }

    const int row = rowBase + r0;
    h[(size_t)(row + 0) * DIM_OUT + lane] = acc0 * dinv[row + 0];
    h[(size_t)(row + 1) * DIM_OUT + lane] = acc1 * dinv[row + 1];
    h[(size_t)(row + 2) * DIM_OUT + lane] = acc2 * dinv[row + 2];
    h[(size_t)(row + 3) * DIM_OUT + lane] = acc3 * dinv[row + 3];
}

// ---------------------------------------------------------------------------
// E: fused per-bucket in-LDS counting sort + register-gather aggregation +
// bias + log_softmax. No f32 atomics anywhere; scalar int LDS atomics only.
// One block (4 waves) per bucket of 64 nodes.
// ---------------------------------------------------------------------------
__global__ __launch_bounds__(256) void kE_agg(const unsigned* __restrict__ pairs,
                                              const int* __restrict__ bstart,
                                              const float* __restrict__ h,
                                              const float* __restrict__ bvec,
                                              float* __restrict__ out) {
    __shared__ unsigned short sidx[CAP];   // bucket-sorted src ids (6 KB)
    __shared__ int cnt[BNODES + 1];        // counts -> exclusive offsets
    __shared__ int cur[BNODES];            // scatter cursors

    const int b = blockIdx.x, t = threadIdx.x;
    const int w = t >> 6, lane = t & 63;
    const int eb = bstart[b], ee = bstart[b + 1];
    const int seg = ee - eb;
    const float bias = bvec[lane];

    if (seg <= CAP) {
        if (t <= BNODES) cnt[t] = 0;
        __syncthreads();

        // pass 1: bucket-local histogram (global reads coalesced, L2-hot)
        for (int i = eb + t; i < ee; i += 256)
            atomicAdd(&cnt[pairs[i] & (BNODES - 1)], 1);
        __syncthreads();

        // wave 0: 64-wide exclusive scan of cnt via shuffles
        if (w == 0) {
            int v = cnt[lane];
            int xs = v;
#pragma unroll
            for (int off = 1; off < 64; off <<= 1) {
                int y = __shfl_up(xs, off);
                if (lane >= off) xs += y;
            }
            cnt[lane] = xs - v;              // exclusive offset
            cur[lane] = xs - v;
            if (lane == 63) cnt[BNODES] = xs; // total = seg
        }
        __syncthreads();

        // pass 2: rank + scatter src into LDS, grouped by dst
        for (int i = eb + t; i < ee; i += 256) {
            unsigned p = pairs[i];
            int pos = atomicAdd(&cur[p & (BNODES - 1)], 1);
            sidx[pos] = (unsigned short)(p >> 16);
        }
        __syncthreads();

        // aggregate: wave w handles nodes r = w, w+4, ... (register acc)
        for (int r = w; r < BNODES; r += 4) {
            const int n = (b << BSHIFT) + r;
            if (n >= N_NODES) break;                 // wave-uniform
            const int s0 = cnt[r], s1 = cnt[r + 1];

            float acc = h[(size_t)n * DIM_OUT + lane];   // self-loop term
            int i = s0;
            for (; i + 4 <= s1; i += 4) {
                const int a0 = sidx[i + 0];
                const int a1 = sidx[i + 1];
                const int a2 = sidx[i + 2];
                const int a3 = sidx[i + 3];
                const float v0 = h[(size_t)a0 * DIM_OUT + lane];
                const float v1 = h[(size_t)a1 * DIM_OUT + lane];
                const float v2 = h[(size_t)a2 * DIM_OUT + lane];
                const float v3 = h[(size_t)a3 * DIM_OUT + lane];
                acc += v0 + v1 + v2 + v3;
            }
            for (; i < s1; ++i) acc += h[(size_t)sidx[i] * DIM_OUT + lane];

            // dinv[n] = rsqrt(deg+1), deg = s1-s0 (exact, from the sort)
            float v = acc * rsqrtf((float)(s1 - s0 + 1)) + bias;

            float m = v;
#pragma unroll
            for (int off = 32; off > 0; off >>= 1) m = fmaxf(m, __shfl_xor(m, off));
            float ex = __expf(v - m);
            float s = ex;
#pragma unroll
            for (int off = 32; off > 0; off >>= 1) s += __shfl_xor(s, off);

            out[(size_t)n * DIM_OUT + lane] = v - m - __logf(s);
        }
    } else {
        // Correctness fallback (statistically unreachable: seg mean 1024, sd 32).
        if (w == 0) {
            for (int r = 0; r < BNODES; ++r) {
                const int n = (b << BSHIFT) + r;
                if (n >= N_NODES) break;
                float acc = h[(size_t)n * DIM_OUT + lane];
                int deg = 0;
                for (int i = eb; i < ee; ++i) {
                    unsigned p = pairs[i];
                    if ((int)(p & (BNODES - 1)) == r) {
                        acc += h[(size_t)(p >> 16) * DIM_OUT + lane];
                        ++deg;
                    }
                }
                float v = acc * rsqrtf((float)(deg + 1)) + bias;
                float m = v;
#pragma unroll
                for (int off = 32; off > 0; off >>= 1) m = fmaxf(m, __shfl_xor(m, off));
                float ex = __expf(v - m);
                float s = ex;
#pragma unroll
                for (int off = 32; off > 0; off >>= 1) s += __shfl_xor(s, off);
                out[(size_t)n * DIM_OUT + lane] = v - m - __logf(s);
            }
        }
    }
}

// ---------------------------------------------------------------------------
extern "C" void kernel_launch(void* const* d_in, const int* in_sizes, int n_in,
                              void* d_out, int out_size, void* d_ws, size_t ws_size,
                              hipStream_t stream) {
    const float* x  = (const float*)d_in[0];
    const int*   ei = (const int*)d_in[1];   // [2, E]: row0 = src, row1 = dst
    const float* W  = (const float*)d_in[2];
    const float* b  = (const float*)d_in[3];
    float* out = (float*)d_out;

    // workspace: h 12.8MB | dinv 200KB | pairs 3.2MB | M 0.8MB | starts 0.8MB | bstart
    char* ws = (char*)d_ws;
    float*    h      = (float*)ws;    ws += (size_t)N_NODES * DIM_OUT * sizeof(float);
    float*    dinv   = (float*)ws;    ws += (size_t)N_NODES * sizeof(float);
    unsigned* pairs  = (unsigned*)ws; ws += (size_t)N_EDGES * sizeof(unsigned);
    int*      M      = (int*)ws;      ws += (size_t)SORTB * NB * sizeof(int);
    int*      starts = (int*)ws;      ws += (size_t)SORTB * NB * sizeof(int);
    int*      bstart = (int*)ws;      ws += (size_t)(NB + 1) * sizeof(int);

    kA_hist   <<<SORTB, 256, 0, stream>>>(ei, M);
    kB1       <<<1, NB, 0, stream>>>(M, bstart);
    kB2       <<<NB, 256, 0, stream>>>(M, bstart, starts);
    kC_scatter<<<SORTB, 256, 0, stream>>>(ei, starts, pairs);
    kD1_deg   <<<NBK, 256, 0, stream>>>(pairs, bstart, dinv);
    k_gemm    <<<N_NODES / 16, 256, 0, stream>>>(x, W, dinv, h);
    kE_agg    <<<NBK, 256, 0, stream>>>(pairs, bstart, h, b, out);
}

// Round 6
// 158.619 us; speedup vs baseline: 3.0560x; 1.2032x over previous
//
#include <hip/hip_runtime.h>
#include <hip/hip_fp16.h>
#include <cstdint>
#include <cstddef>

#define N_NODES 50000
#define N_EDGES 800000
#define DIM_IN  128
#define DIM_OUT 64

#define NB      1024                               // padded bucket count (pow2)
#define BSHIFT  6                                  // 64 nodes per bucket
#define BNODES  64
#define NBK     ((N_NODES + BNODES - 1) / BNODES)  // 782 buckets actually used
#define EB      4096                               // edges per sort tile
#define SORTB   ((N_EDGES + EB - 1) / EB)          // 196 sort tiles
#define CAP     3072                               // in-LDS bucket capacity (mean 1024, sd 32)
#define GROWS   128                                // gemm rows per block

typedef _Float16 f16x8 __attribute__((ext_vector_type(8)));
typedef float    f32x4 __attribute__((ext_vector_type(4)));

// ---------------------------------------------------------------------------
// A: per-tile histogram over coarse dst-buckets (scalar LDS int atomics).
// ---------------------------------------------------------------------------
__global__ __launch_bounds__(256) void kA_hist(const int* __restrict__ ei,
                                               int* __restrict__ M) {
    __shared__ int hcnt[NB];
    const int t = threadIdx.x, blk = blockIdx.x;
    for (int i = t; i < NB; i += 256) hcnt[i] = 0;
    __syncthreads();
    const int base = blk * EB;
#pragma unroll
    for (int it = 0; it < EB / 256; ++it) {
        int e = base + it * 256 + t;
        if (e < N_EDGES) atomicAdd(&hcnt[ei[N_EDGES + e] >> BSHIFT], 1);
    }
    __syncthreads();
    for (int i = t; i < NB; i += 256) M[blk * NB + i] = hcnt[i];
}

// ---------------------------------------------------------------------------
// B1: one block. bucket totals (sum over tiles) -> exclusive bucket starts.
// ---------------------------------------------------------------------------
__global__ __launch_bounds__(NB) void kB1(const int* __restrict__ M,
                                          int* __restrict__ bstart) {
    __shared__ int s[NB];
    const int t = threadIdx.x;
    int sum = 0;
#pragma unroll 8
    for (int blk = 0; blk < SORTB; ++blk) sum += M[blk * NB + t];
    s[t] = sum;
    __syncthreads();
    for (int off = 1; off < NB; off <<= 1) {
        int add = (t >= off) ? s[t - off] : 0;
        __syncthreads();
        s[t] += add;
        __syncthreads();
    }
    bstart[t] = s[t] - sum;                 // exclusive
    if (t == NB - 1) bstart[NB] = s[t];     // total (= N_EDGES)
}

// ---------------------------------------------------------------------------
// B2: per-bucket exclusive prefix over tiles -> starts[tile][bucket].
// ---------------------------------------------------------------------------
__global__ __launch_bounds__(256) void kB2(const int* __restrict__ M,
                                           const int* __restrict__ bstart,
                                           int* __restrict__ starts) {
    __shared__ int s[256];
    const int b = blockIdx.x, t = threadIdx.x;
    const int v = (t < SORTB) ? M[t * NB + b] : 0;
    s[t] = v;
    __syncthreads();
    for (int off = 1; off < 256; off <<= 1) {
        int add = (t >= off) ? s[t - off] : 0;
        __syncthreads();
        s[t] += add;
        __syncthreads();
    }
    if (t < SORTB) starts[t * NB + b] = bstart[b] + s[t] - v;
}

// ---------------------------------------------------------------------------
// C: scatter packed (src<<16)|dst into bucket segments. LDS cursor atomics,
// plain write-back global stores. No global atomics.
// ---------------------------------------------------------------------------
__global__ __launch_bounds__(256) void kC_scatter(const int* __restrict__ ei,
                                                  const int* __restrict__ starts,
                                                  unsigned* __restrict__ pairs) {
    __shared__ int cur[NB];
    const int t = threadIdx.x, blk = blockIdx.x;
    for (int i = t; i < NB; i += 256) cur[i] = starts[blk * NB + i];
    __syncthreads();
    const int base = blk * EB;
#pragma unroll
    for (int it = 0; it < EB / 256; ++it) {
        int e = base + it * 256 + t;
        if (e < N_EDGES) {
            unsigned src = (unsigned)ei[e];
            unsigned dst = (unsigned)ei[N_EDGES + e];
            int pos = atomicAdd(&cur[dst >> BSHIFT], 1);
            pairs[pos] = (src << 16) | dst;   // both < 2^16
        }
    }
}

// ---------------------------------------------------------------------------
// D1: per-bucket degree count -> dinv = rsqrt(deg+1) (needed by gemm).
// ---------------------------------------------------------------------------
__global__ __launch_bounds__(256) void kD1_deg(const unsigned* __restrict__ pairs,
                                               const int* __restrict__ bstart,
                                               float* __restrict__ dinv) {
    __shared__ int cnt[BNODES];
    const int b = blockIdx.x, t = threadIdx.x;
    if (t < BNODES) cnt[t] = 0;
    __syncthreads();
    const int eb = bstart[b], ee = bstart[b + 1];
    for (int i = eb + t; i < ee; i += 256)
        atomicAdd(&cnt[pairs[i] & (BNODES - 1)], 1);
    __syncthreads();
    if (t < BNODES) {
        int n = (b << BSHIFT) + t;
        if (n < N_NODES) dinv[n] = rsqrtf((float)(cnt[t] + 1));
    }
}

// ---------------------------------------------------------------------------
// GEMM via f16 MFMA: h[n,:] = (half)((x[n,:] @ W) * dinv[n]).
// No LDS. B-frags (all of W, f16) in 64 VGPRs/wave, loaded once.
// A-frags straight from global in MFMA layout. 391 blocks x 128 rows.
// MFMA 16x16x32_f16 layouts: A[m=lane&15][k=quad*8+j]; B[k=quad*8+j][n=lane&15];
// C/D: row=quad*4+reg, col=lane&15  (m89-verified mapping).
// ---------------------------------------------------------------------------
__global__ __launch_bounds__(256) void k_gemm(const float* __restrict__ x,
                                              const float* __restrict__ W,
                                              const float* __restrict__ dinv,
                                              __half* __restrict__ h) {
    const int t = threadIdx.x;
    const int w = t >> 6;
    const int l = t & 63;
    const int q = l >> 4;       // quad 0..3
    const int m16 = l & 15;

    // B fragments: bf[kc][ct], lane holds W[kc*32+q*8+j][ct*16+m16], j=0..7
    f16x8 bf[4][4];
#pragma unroll
    for (int kc = 0; kc < 4; ++kc)
#pragma unroll
        for (int ct = 0; ct < 4; ++ct) {
            const float* wp = W + (size_t)(kc * 32 + q * 8) * DIM_OUT + ct * 16 + m16;
            f16x8 v;
#pragma unroll
            for (int j = 0; j < 8; ++j) v[j] = (_Float16)wp[(size_t)j * DIM_OUT];
            bf[kc][ct] = v;
        }

    const int base = blockIdx.x * GROWS + w * 32;
#pragma unroll
    for (int rt = 0; rt < 2; ++rt) {
        const int m0 = base + rt * 16;
        int mrow = m0 + m16;
        if (mrow >= N_NODES) mrow = N_NODES - 1;   // clamp (stores guarded)

        f16x8 af[4];
#pragma unroll
        for (int kc = 0; kc < 4; ++kc) {
            const float4* xp = (const float4*)(x + (size_t)mrow * DIM_IN + kc * 32 + q * 8);
            const float4 p0 = xp[0], p1 = xp[1];
            f16x8 a;
            a[0] = (_Float16)p0.x; a[1] = (_Float16)p0.y;
            a[2] = (_Float16)p0.z; a[3] = (_Float16)p0.w;
            a[4] = (_Float16)p1.x; a[5] = (_Float16)p1.y;
            a[6] = (_Float16)p1.z; a[7] = (_Float16)p1.w;
            af[kc] = a;
        }

        f32x4 acc[4];
#pragma unroll
        for (int ct = 0; ct < 4; ++ct) acc[ct] = (f32x4){0.f, 0.f, 0.f, 0.f};
#pragma unroll
        for (int kc = 0; kc < 4; ++kc)
#pragma unroll
            for (int ct = 0; ct < 4; ++ct)
                acc[ct] = __builtin_amdgcn_mfma_f32_16x16x32_f16(af[kc], bf[kc][ct], acc[ct], 0, 0, 0);

#pragma unroll
        for (int reg = 0; reg < 4; ++reg) {
            const int r = m0 + q * 4 + reg;
            if (r < N_NODES) {
                const float d = dinv[r];
#pragma unroll
                for (int ct = 0; ct < 4; ++ct)
                    h[(size_t)r * DIM_OUT + ct * 16 + m16] = __float2half(acc[ct][reg] * d);
            }
        }
    }
}

// ---------------------------------------------------------------------------
// E: fused per-bucket in-LDS counting sort + half-wave register-gather
// aggregation (h in f16, lane reads __half2 = 2 channels) + bias +
// log_softmax. Scalar int LDS atomics only.
// ---------------------------------------------------------------------------
__global__ __launch_bounds__(256) void kE_agg(const unsigned* __restrict__ pairs,
                                              const int* __restrict__ bstart,
                                              const __half* __restrict__ h,
                                              const float* __restrict__ bvec,
                                              float* __restrict__ out) {
    __shared__ unsigned short sidx[CAP];   // bucket-sorted src ids (6 KB)
    __shared__ int cnt[BNODES + 1];        // counts -> exclusive offsets
    __shared__ int cur[BNODES];            // scatter cursors

    const int b = blockIdx.x, t = threadIdx.x;
    const int w = t >> 6, lane = t & 63;
    const int hw = t >> 5, sl = t & 31;    // half-wave id / sub-lane
    const int eb = bstart[b], ee = bstart[b + 1];
    const int seg = ee - eb;

    if (seg <= CAP) {
        if (t <= BNODES) cnt[t] = 0;
        __syncthreads();

        // pass 1: bucket-local histogram
        for (int i = eb + t; i < ee; i += 256)
            atomicAdd(&cnt[pairs[i] & (BNODES - 1)], 1);
        __syncthreads();

        // wave 0: 64-wide exclusive scan of cnt via shuffles
        if (w == 0) {
            int v = cnt[lane];
            int xs = v;
#pragma unroll
            for (int off = 1; off < 64; off <<= 1) {
                int y = __shfl_up(xs, off);
                if (lane >= off) xs += y;
            }
            cnt[lane] = xs - v;               // exclusive offset
            cur[lane] = xs - v;
            if (lane == 63) cnt[BNODES] = xs; // total = seg
        }
        __syncthreads();

        // pass 2: rank + scatter src into LDS, grouped by dst
        for (int i = eb + t; i < ee; i += 256) {
            unsigned p = pairs[i];
            int pos = atomicAdd(&cur[p & (BNODES - 1)], 1);
            sidx[pos] = (unsigned short)(p >> 16);
        }
        __syncthreads();

        // aggregate: half-wave hw handles nodes r = hw, hw+8, ...
        const __half2* __restrict__ h2 = (const __half2*)h;  // [n*32 + sl]
        const float2 bias = *(const float2*)&bvec[2 * sl];
        for (int r = hw; r < BNODES; r += 8) {
            const int n = (b << BSHIFT) + r;
            if (n >= N_NODES) break;                 // half-wave-uniform
            const int s0 = cnt[r], s1 = cnt[r + 1];

            float2 acc = __half22float2(h2[n * 32 + sl]);   // self-loop term
            int i = s0;
            for (; i + 4 <= s1; i += 4) {
                const int a0 = sidx[i + 0];
                const int a1 = sidx[i + 1];
                const int a2 = sidx[i + 2];
                const int a3 = sidx[i + 3];
                const float2 v0 = __half22float2(h2[a0 * 32 + sl]);
                const float2 v1 = __half22float2(h2[a1 * 32 + sl]);
                const float2 v2 = __half22float2(h2[a2 * 32 + sl]);
                const float2 v3 = __half22float2(h2[a3 * 32 + sl]);
                acc.x += v0.x + v1.x + v2.x + v3.x;
                acc.y += v0.y + v1.y + v2.y + v3.y;
            }
            for (; i < s1; ++i) {
                const float2 v0 = __half22float2(h2[sidx[i] * 32 + sl]);
                acc.x += v0.x; acc.y += v0.y;
            }

            const float di = rsqrtf((float)(s1 - s0 + 1));
            float vx = acc.x * di + bias.x;
            float vy = acc.y * di + bias.y;

            float m = fmaxf(vx, vy);
#pragma unroll
            for (int off = 16; off > 0; off >>= 1) m = fmaxf(m, __shfl_xor(m, off));
            float s = __expf(vx - m) + __expf(vy - m);
#pragma unroll
            for (int off = 16; off > 0; off >>= 1) s += __shfl_xor(s, off);
            const float ls = __logf(s);

            float2 o; o.x = vx - m - ls; o.y = vy - m - ls;
            *(float2*)&out[(size_t)n * DIM_OUT + 2 * sl] = o;
        }
    } else {
        // Correctness fallback (statistically unreachable: seg mean 1024, sd 32).
        if (w == 0) {
            const float bias = bvec[lane];
            for (int r = 0; r < BNODES; ++r) {
                const int n = (b << BSHIFT) + r;
                if (n >= N_NODES) break;
                float acc = __half2float(h[(size_t)n * DIM_OUT + lane]);
                int deg = 0;
                for (int i = eb; i < ee; ++i) {
                    unsigned p = pairs[i];
                    if ((int)(p & (BNODES - 1)) == r) {
                        acc += __half2float(h[(size_t)(p >> 16) * DIM_OUT + lane]);
                        ++deg;
                    }
                }
                float v = acc * rsqrtf((float)(deg + 1)) + bias;
                float m = v;
#pragma unroll
                for (int off = 32; off > 0; off >>= 1) m = fmaxf(m, __shfl_xor(m, off));
                float ex = __expf(v - m);
                float s = ex;
#pragma unroll
                for (int off = 32; off > 0; off >>= 1) s += __shfl_xor(s, off);
                out[(size_t)n * DIM_OUT + lane] = v - m - __logf(s);
            }
        }
    }
}

// ---------------------------------------------------------------------------
extern "C" void kernel_launch(void* const* d_in, const int* in_sizes, int n_in,
                              void* d_out, int out_size, void* d_ws, size_t ws_size,
                              hipStream_t stream) {
    const float* x  = (const float*)d_in[0];
    const int*   ei = (const int*)d_in[1];   // [2, E]: row0 = src, row1 = dst
    const float* W  = (const float*)d_in[2];
    const float* b  = (const float*)d_in[3];
    float* out = (float*)d_out;

    // workspace: h 6.4MB (f16) | dinv 200KB | pairs 3.2MB | M 0.8MB | starts 0.8MB | bstart
    char* ws = (char*)d_ws;
    __half*   h      = (__half*)ws;   ws += (size_t)N_NODES * DIM_OUT * sizeof(__half);
    float*    dinv   = (float*)ws;    ws += (size_t)N_NODES * sizeof(float);
    unsigned* pairs  = (unsigned*)ws; ws += (size_t)N_EDGES * sizeof(unsigned);
    int*      M      = (int*)ws;      ws += (size_t)SORTB * NB * sizeof(int);
    int*      starts = (int*)ws;      ws += (size_t)SORTB * NB * sizeof(int);
    int*      bstart = (int*)ws;      ws += (size_t)(NB + 1) * sizeof(int);

    kA_hist   <<<SORTB, 256, 0, stream>>>(ei, M);
    kB1       <<<1, NB, 0, stream>>>(M, bstart);
    kB2       <<<NB, 256, 0, stream>>>(M, bstart, starts);
    kC_scatter<<<SORTB, 256, 0, stream>>>(ei, starts, pairs);
    kD1_deg   <<<NBK, 256, 0, stream>>>(pairs, bstart, dinv);
    k_gemm    <<<(N_NODES + GROWS - 1) / GROWS, 256, 0, stream>>>(x, W, dinv, h);
    kE_agg    <<<NBK, 256, 0, stream>>>(pairs, bstart, h, b, out);
}

// Round 7
// 138.617 us; speedup vs baseline: 3.4970x; 1.1443x over previous
//
#include <hip/hip_runtime.h>
#include <hip/hip_fp16.h>
#include <cstdint>
#include <cstddef>

#define N_NODES 50000
#define N_EDGES 800000
#define DIM_IN  128
#define DIM_OUT 64

#define BSHIFT  5                                  // 32 nodes per bucket
#define BNODES  32
#define NB      2048                               // padded bucket count (pow2)
#define NBK     ((N_NODES + BNODES - 1) / BNODES)  // 1563 buckets used
#define EB      4096                               // edges per sort tile
#define SORTB   ((N_EDGES + EB - 1) / EB)          // 196 sort tiles
#define NE4     (N_EDGES / 4)                      // 200000 int4 edge groups
#define GROWS   128                                // gemm rows per block

typedef _Float16 f16x8 __attribute__((ext_vector_type(8)));
typedef float    f32x4 __attribute__((ext_vector_type(4)));

// ---------------------------------------------------------------------------
// A: per-tile histogram over coarse dst-buckets (scalar LDS int atomics),
// int4 edge loads.
// ---------------------------------------------------------------------------
__global__ __launch_bounds__(256) void kA_hist(const int* __restrict__ ei,
                                               int* __restrict__ M) {
    __shared__ int hcnt[NB];
    const int t = threadIdx.x, blk = blockIdx.x;
    for (int i = t; i < NB; i += 256) hcnt[i] = 0;
    __syncthreads();
    const int4* dst4 = (const int4*)(ei + N_EDGES);
#pragma unroll
    for (int it = 0; it < EB / 1024; ++it) {
        const int g = blk * (EB / 4) + it * 256 + t;
        if (g < NE4) {
            const int4 d = dst4[g];
            atomicAdd(&hcnt[d.x >> BSHIFT], 1);
            atomicAdd(&hcnt[d.y >> BSHIFT], 1);
            atomicAdd(&hcnt[d.z >> BSHIFT], 1);
            atomicAdd(&hcnt[d.w >> BSHIFT], 1);
        }
    }
    __syncthreads();
    for (int i = t; i < NB; i += 256) M[blk * NB + i] = hcnt[i];
}

// ---------------------------------------------------------------------------
// B-tile: per bucket, exclusive scan of M over tiles -> startsL (local),
// column total -> colsum. 2048 blocks (spreads the 1.6 MB M read).
// ---------------------------------------------------------------------------
__global__ __launch_bounds__(256) void kB_tile(const int* __restrict__ M,
                                               int* __restrict__ startsL,
                                               int* __restrict__ colsum) {
    __shared__ int s[256];
    const int b = blockIdx.x, t = threadIdx.x;
    const int v = (t < SORTB) ? M[(size_t)t * NB + b] : 0;
    s[t] = v;
    __syncthreads();
    for (int off = 1; off < 256; off <<= 1) {
        int add = (t >= off) ? s[t - off] : 0;
        __syncthreads();
        s[t] += add;
        __syncthreads();
    }
    if (t < SORTB) startsL[(size_t)t * NB + b] = s[t] - v;
    if (t == 255) colsum[b] = s[255];
}

// ---------------------------------------------------------------------------
// B-scan: one block, 1024 threads, scans colsum[2048] (8 KB) -> bstart.
// Each thread owns a bucket pair.
// ---------------------------------------------------------------------------
__global__ __launch_bounds__(1024) void kB_scan(const int* __restrict__ colsum,
                                                int* __restrict__ bstart) {
    __shared__ int s[1024];
    const int t = threadIdx.x;
    const int2 v2 = ((const int2*)colsum)[t];
    const int pair = v2.x + v2.y;
    s[t] = pair;
    __syncthreads();
    for (int off = 1; off < 1024; off <<= 1) {
        int add = (t >= off) ? s[t - off] : 0;
        __syncthreads();
        s[t] += add;
        __syncthreads();
    }
    const int excl = s[t] - pair;
    bstart[2 * t]     = excl;
    bstart[2 * t + 1] = excl + v2.x;
    if (t == 1023) bstart[NB] = s[1023];   // = N_EDGES
}

// ---------------------------------------------------------------------------
// C: scatter packed (src<<16)|dst into bucket segments. LDS cursor atomics,
// int4 edge loads, plain global stores.
// ---------------------------------------------------------------------------
__global__ __launch_bounds__(256) void kC_scatter(const int* __restrict__ ei,
                                                  const int* __restrict__ startsL,
                                                  const int* __restrict__ bstart,
                                                  unsigned* __restrict__ pairs) {
    __shared__ int cur[NB];
    const int t = threadIdx.x, blk = blockIdx.x;
    for (int i = t; i < NB; i += 256)
        cur[i] = bstart[i] + startsL[(size_t)blk * NB + i];
    __syncthreads();
    const int4* src4 = (const int4*)ei;
    const int4* dst4 = (const int4*)(ei + N_EDGES);
#pragma unroll
    for (int it = 0; it < EB / 1024; ++it) {
        const int g = blk * (EB / 4) + it * 256 + t;
        if (g < NE4) {
            const int4 sv = src4[g];
            const int4 dv = dst4[g];
            int p;
            p = atomicAdd(&cur[dv.x >> BSHIFT], 1); pairs[p] = ((unsigned)sv.x << 16) | (unsigned)dv.x;
            p = atomicAdd(&cur[dv.y >> BSHIFT], 1); pairs[p] = ((unsigned)sv.y << 16) | (unsigned)dv.y;
            p = atomicAdd(&cur[dv.z >> BSHIFT], 1); pairs[p] = ((unsigned)sv.z << 16) | (unsigned)dv.z;
            p = atomicAdd(&cur[dv.w >> BSHIFT], 1); pairs[p] = ((unsigned)sv.w << 16) | (unsigned)dv.w;
        }
    }
}

// ---------------------------------------------------------------------------
// Sort: per bucket, node-granular counting sort into global csr (ushort),
// emitting nodeoff (global CSR offsets) and dinv = rsqrt(deg+1).
// No capacity limit: scatter goes straight to global.
// ---------------------------------------------------------------------------
__global__ __launch_bounds__(256) void kSort(const unsigned* __restrict__ pairs,
                                             const int* __restrict__ bstart,
                                             unsigned short* __restrict__ csr,
                                             int* __restrict__ nodeoff,
                                             float* __restrict__ dinv) {
    __shared__ int cnt[BNODES];
    __shared__ int cur[BNODES];
    const int b = blockIdx.x, t = threadIdx.x;
    const int eb = bstart[b], ee = bstart[b + 1];

    if (t < BNODES) cnt[t] = 0;
    __syncthreads();

    for (int i = eb + t; i < ee; i += 256)
        atomicAdd(&cnt[pairs[i] & (BNODES - 1)], 1);
    __syncthreads();

    if (t < 64) {                      // wave 0: 32-wide shuffle scan
        const int lane = t;            // lanes 0..31 carry data
        const int v = (lane < BNODES) ? cnt[lane] : 0;
        int xs = v;
#pragma unroll
        for (int off = 1; off < BNODES; off <<= 1) {
            int y = __shfl_up(xs, off);
            if (lane >= off) xs += y;
        }
        if (lane < BNODES) {
            const int excl = xs - v;
            cur[lane] = eb + excl;
            const int n = (b << BSHIFT) + lane;
            if (n <= N_NODES) nodeoff[n] = eb + excl;
            if (n < N_NODES)  dinv[n] = rsqrtf((float)(v + 1));
        }
    }
    __syncthreads();

    for (int i = eb + t; i < ee; i += 256) {
        const unsigned p = pairs[i];
        const int pos = atomicAdd(&cur[p & (BNODES - 1)], 1);
        csr[pos] = (unsigned short)(p >> 16);
    }
}

// ---------------------------------------------------------------------------
// GEMM via f16 MFMA: h[n,:] = (half)((x[n,:] @ W) * dinv[n]).
// B-frags (all of W) in VGPRs once/wave; A-frags straight from global.
// MFMA 16x16x32_f16: A[m=lane&15][k=quad*8+j]; B[k][n=lane&15];
// C/D: row=quad*4+reg, col=lane&15 (m89-verified; validated R6, absmax 0.031).
// ---------------------------------------------------------------------------
__global__ __launch_bounds__(256) void k_gemm(const float* __restrict__ x,
                                              const float* __restrict__ W,
                                              const float* __restrict__ dinv,
                                              __half* __restrict__ h) {
    const int t = threadIdx.x;
    const int w = t >> 6;
    const int l = t & 63;
    const int q = l >> 4;
    const int m16 = l & 15;

    f16x8 bf[4][4];
#pragma unroll
    for (int kc = 0; kc < 4; ++kc)
#pragma unroll
        for (int ct = 0; ct < 4; ++ct) {
            const float* wp = W + (size_t)(kc * 32 + q * 8) * DIM_OUT + ct * 16 + m16;
            f16x8 v;
#pragma unroll
            for (int j = 0; j < 8; ++j) v[j] = (_Float16)wp[(size_t)j * DIM_OUT];
            bf[kc][ct] = v;
        }

    const int base = blockIdx.x * GROWS + w * 32;
#pragma unroll
    for (int rt = 0; rt < 2; ++rt) {
        const int m0 = base + rt * 16;
        int mrow = m0 + m16;
        if (mrow >= N_NODES) mrow = N_NODES - 1;   // clamp (stores guarded)

        f16x8 af[4];
#pragma unroll
        for (int kc = 0; kc < 4; ++kc) {
            const float4* xp = (const float4*)(x + (size_t)mrow * DIM_IN + kc * 32 + q * 8);
            const float4 p0 = xp[0], p1 = xp[1];
            f16x8 a;
            a[0] = (_Float16)p0.x; a[1] = (_Float16)p0.y;
            a[2] = (_Float16)p0.z; a[3] = (_Float16)p0.w;
            a[4] = (_Float16)p1.x; a[5] = (_Float16)p1.y;
            a[6] = (_Float16)p1.z; a[7] = (_Float16)p1.w;
            af[kc] = a;
        }

        f32x4 acc[4];
#pragma unroll
        for (int ct = 0; ct < 4; ++ct) acc[ct] = (f32x4){0.f, 0.f, 0.f, 0.f};
#pragma unroll
        for (int kc = 0; kc < 4; ++kc)
#pragma unroll
            for (int ct = 0; ct < 4; ++ct)
                acc[ct] = __builtin_amdgcn_mfma_f32_16x16x32_f16(af[kc], bf[kc][ct], acc[ct], 0, 0, 0);

#pragma unroll
        for (int reg = 0; reg < 4; ++reg) {
            const int r = m0 + q * 4 + reg;
            if (r < N_NODES) {
                const float d = dinv[r];
#pragma unroll
                for (int ct = 0; ct < 4; ++ct)
                    h[(size_t)r * DIM_OUT + ct * 16 + m16] = __float2half(acc[ct][reg] * d);
            }
        }
    }
}

// ---------------------------------------------------------------------------
// E: pure CSR gather + bias + log_softmax. Half-wave per node (lane = 2
// channels via __half2). 6250 blocks — full wave-capacity occupancy.
// out[n] = logsoftmax(dinv[n]*(h[n] + sum_src h[src]) + b)
// ---------------------------------------------------------------------------
__global__ __launch_bounds__(256) void kE_agg(const int* __restrict__ nodeoff,
                                              const unsigned short* __restrict__ csr,
                                              const __half* __restrict__ h,
                                              const float* __restrict__ bvec,
                                              float* __restrict__ out) {
    const int t = threadIdx.x;
    const int hw = t >> 5, sl = t & 31;
    const int n = blockIdx.x * 8 + hw;       // 6250*8 = 50000 exactly
    const __half2* __restrict__ h2 = (const __half2*)h;

    const int s0 = nodeoff[n], s1 = nodeoff[n + 1];
    float2 acc = __half22float2(h2[n * 32 + sl]);   // self-loop term

    int i = s0;
    for (; i + 4 <= s1; i += 4) {
        const int a0 = csr[i + 0];
        const int a1 = csr[i + 1];
        const int a2 = csr[i + 2];
        const int a3 = csr[i + 3];
        const float2 v0 = __half22float2(h2[a0 * 32 + sl]);
        const float2 v1 = __half22float2(h2[a1 * 32 + sl]);
        const float2 v2 = __half22float2(h2[a2 * 32 + sl]);
        const float2 v3 = __half22float2(h2[a3 * 32 + sl]);
        acc.x += v0.x + v1.x + v2.x + v3.x;
        acc.y += v0.y + v1.y + v2.y + v3.y;
    }
    for (; i < s1; ++i) {
        const float2 v0 = __half22float2(h2[csr[i] * 32 + sl]);
        acc.x += v0.x; acc.y += v0.y;
    }

    const float2 bias = *(const float2*)&bvec[2 * sl];
    const float di = rsqrtf((float)(s1 - s0 + 1));
    float vx = acc.x * di + bias.x;
    float vy = acc.y * di + bias.y;

    float m = fmaxf(vx, vy);
#pragma unroll
    for (int off = 16; off > 0; off >>= 1) m = fmaxf(m, __shfl_xor(m, off));
    float s = __expf(vx - m) + __expf(vy - m);
#pragma unroll
    for (int off = 16; off > 0; off >>= 1) s += __shfl_xor(s, off);
    const float ls = __logf(s);

    float2 o; o.x = vx - m - ls; o.y = vy - m - ls;
    *(float2*)&out[(size_t)n * DIM_OUT + 2 * sl] = o;
}

// ---------------------------------------------------------------------------
extern "C" void kernel_launch(void* const* d_in, const int* in_sizes, int n_in,
                              void* d_out, int out_size, void* d_ws, size_t ws_size,
                              hipStream_t stream) {
    const float* x  = (const float*)d_in[0];
    const int*   ei = (const int*)d_in[1];   // [2, E]: row0 = src, row1 = dst
    const float* W  = (const float*)d_in[2];
    const float* b  = (const float*)d_in[3];
    float* out = (float*)d_out;

    // workspace layout (~15 MB of 256 MB):
    char* ws = (char*)d_ws;
    __half*         h       = (__half*)ws;         ws += (size_t)N_NODES * DIM_OUT * sizeof(__half);
    float*          dinv    = (float*)ws;          ws += (size_t)N_NODES * sizeof(float);
    unsigned*       pairs   = (unsigned*)ws;       ws += (size_t)N_EDGES * sizeof(unsigned);
    unsigned short* csr     = (unsigned short*)ws; ws += (size_t)N_EDGES * sizeof(unsigned short);
    int*            nodeoff = (int*)ws;            ws += (size_t)(N_NODES + 1) * sizeof(int);
    ws = (char*)(((uintptr_t)ws + 15) & ~(uintptr_t)15);
    int*            M       = (int*)ws;            ws += (size_t)SORTB * NB * sizeof(int);
    int*            startsL = (int*)ws;            ws += (size_t)SORTB * NB * sizeof(int);
    int*            colsum  = (int*)ws;            ws += (size_t)NB * sizeof(int);
    int*            bstart  = (int*)ws;            ws += (size_t)(NB + 1) * sizeof(int);

    kA_hist   <<<SORTB, 256, 0, stream>>>(ei, M);
    kB_tile   <<<NB, 256, 0, stream>>>(M, startsL, colsum);
    kB_scan   <<<1, 1024, 0, stream>>>(colsum, bstart);
    kC_scatter<<<SORTB, 256, 0, stream>>>(ei, startsL, bstart, pairs);
    kSort     <<<NBK, 256, 0, stream>>>(pairs, bstart, csr, nodeoff, dinv);
    k_gemm    <<<(N_NODES + GROWS - 1) / GROWS, 256, 0, stream>>>(x, W, dinv, h);
    kE_agg    <<<N_NODES / 8, 256, 0, stream>>>(nodeoff, csr, h, b, out);
}

// Round 8
// 131.937 us; speedup vs baseline: 3.6740x; 1.0506x over previous
//
#include <hip/hip_runtime.h>
#include <hip/hip_fp16.h>
#include <cstdint>
#include <cstddef>

#define N_NODES 50000
#define N_EDGES 800000
#define DIM_IN  128
#define DIM_OUT 64

#define BSHIFT  5                                  // 32 nodes per bucket
#define BNODES  32
#define NB      2048                               // padded bucket count (pow2)
#define NBK     ((N_NODES + BNODES - 1) / BNODES)  // 1563 buckets used
#define EB      8192                               // edges per sort tile
#define SORTB   ((N_EDGES + EB - 1) / EB)          // 98 sort tiles
#define NE4     (N_EDGES / 4)                      // 200000 int4 edge groups
#define GROWS   128                                // gemm rows per block

typedef _Float16 f16x8 __attribute__((ext_vector_type(8)));
typedef _Float16 f16x4 __attribute__((ext_vector_type(4)));
typedef float    f32x4 __attribute__((ext_vector_type(4)));

// ---------------------------------------------------------------------------
// A: per-tile histogram over coarse dst-buckets (scalar LDS int atomics),
// int4 edge loads. 98 tiles x 8192 edges.
// ---------------------------------------------------------------------------
__global__ __launch_bounds__(256) void kA_hist(const int* __restrict__ ei,
                                               int* __restrict__ M) {
    __shared__ int hcnt[NB];
    const int t = threadIdx.x, blk = blockIdx.x;
    for (int i = t; i < NB; i += 256) hcnt[i] = 0;
    __syncthreads();
    const int4* dst4 = (const int4*)(ei + N_EDGES);
#pragma unroll
    for (int it = 0; it < EB / 1024; ++it) {
        const int g = blk * (EB / 4) + it * 256 + t;
        if (g < NE4) {
            const int4 d = dst4[g];
            atomicAdd(&hcnt[d.x >> BSHIFT], 1);
            atomicAdd(&hcnt[d.y >> BSHIFT], 1);
            atomicAdd(&hcnt[d.z >> BSHIFT], 1);
            atomicAdd(&hcnt[d.w >> BSHIFT], 1);
        }
    }
    __syncthreads();
    for (int i = t; i < NB; i += 256) M[blk * NB + i] = hcnt[i];
}

// ---------------------------------------------------------------------------
// B-tile: per bucket, exclusive scan of M over tiles -> startsL (local),
// column total -> colsum. 2048 blocks.
// ---------------------------------------------------------------------------
__global__ __launch_bounds__(256) void kB_tile(const int* __restrict__ M,
                                               int* __restrict__ startsL,
                                               int* __restrict__ colsum) {
    __shared__ int s[256];
    const int b = blockIdx.x, t = threadIdx.x;
    const int v = (t < SORTB) ? M[(size_t)t * NB + b] : 0;
    s[t] = v;
    __syncthreads();
    for (int off = 1; off < 256; off <<= 1) {
        int add = (t >= off) ? s[t - off] : 0;
        __syncthreads();
        s[t] += add;
        __syncthreads();
    }
    if (t < SORTB) startsL[(size_t)t * NB + b] = s[t] - v;
    if (t == 255) colsum[b] = s[255];
}

// ---------------------------------------------------------------------------
// B-scan: one block, 1024 threads, scans colsum[2048] (8 KB) -> bstart.
// ---------------------------------------------------------------------------
__global__ __launch_bounds__(1024) void kB_scan(const int* __restrict__ colsum,
                                                int* __restrict__ bstart) {
    __shared__ int s[1024];
    const int t = threadIdx.x;
    const int2 v2 = ((const int2*)colsum)[t];
    const int pair = v2.x + v2.y;
    s[t] = pair;
    __syncthreads();
    for (int off = 1; off < 1024; off <<= 1) {
        int add = (t >= off) ? s[t - off] : 0;
        __syncthreads();
        s[t] += add;
        __syncthreads();
    }
    const int excl = s[t] - pair;
    bstart[2 * t]     = excl;
    bstart[2 * t + 1] = excl + v2.x;
    if (t == 1023) bstart[NB] = s[1023];   // = N_EDGES
}

// ---------------------------------------------------------------------------
// C: scatter packed (src<<16)|dst into bucket segments. LDS cursor atomics,
// int4 edge loads, plain global stores. Bigger tiles (8192) halve the
// partial-line sharing on the pairs buffer vs EB=4096.
// ---------------------------------------------------------------------------
__global__ __launch_bounds__(256) void kC_scatter(const int* __restrict__ ei,
                                                  const int* __restrict__ startsL,
                                                  const int* __restrict__ bstart,
                                                  unsigned* __restrict__ pairs) {
    __shared__ int cur[NB];
    const int t = threadIdx.x, blk = blockIdx.x;
    for (int i = t; i < NB; i += 256)
        cur[i] = bstart[i] + startsL[(size_t)blk * NB + i];
    __syncthreads();
    const int4* src4 = (const int4*)ei;
    const int4* dst4 = (const int4*)(ei + N_EDGES);
#pragma unroll
    for (int it = 0; it < EB / 1024; ++it) {
        const int g = blk * (EB / 4) + it * 256 + t;
        if (g < NE4) {
            const int4 sv = src4[g];
            const int4 dv = dst4[g];
            int p;
            p = atomicAdd(&cur[dv.x >> BSHIFT], 1); pairs[p] = ((unsigned)sv.x << 16) | (unsigned)dv.x;
            p = atomicAdd(&cur[dv.y >> BSHIFT], 1); pairs[p] = ((unsigned)sv.y << 16) | (unsigned)dv.y;
            p = atomicAdd(&cur[dv.z >> BSHIFT], 1); pairs[p] = ((unsigned)sv.z << 16) | (unsigned)dv.z;
            p = atomicAdd(&cur[dv.w >> BSHIFT], 1); pairs[p] = ((unsigned)sv.w << 16) | (unsigned)dv.w;
        }
    }
}

// ---------------------------------------------------------------------------
// Sort: per bucket, node-granular counting sort into global csr (ushort),
// emitting nodeoff (global CSR offsets) and dinv = rsqrt(deg+1).
// 4-deep unrolled passes keep independent loads in flight.
// ---------------------------------------------------------------------------
__global__ __launch_bounds__(256) void kSort(const unsigned* __restrict__ pairs,
                                             const int* __restrict__ bstart,
                                             unsigned short* __restrict__ csr,
                                             int* __restrict__ nodeoff,
                                             float* __restrict__ dinv) {
    __shared__ int cnt[BNODES];
    __shared__ int cur[BNODES];
    const int b = blockIdx.x, t = threadIdx.x;
    const int eb = bstart[b], ee = bstart[b + 1];

    if (t < BNODES) cnt[t] = 0;
    __syncthreads();

    {
        int i = eb + t;
        for (; i + 768 < ee; i += 1024) {
            const unsigned p0 = pairs[i];
            const unsigned p1 = pairs[i + 256];
            const unsigned p2 = pairs[i + 512];
            const unsigned p3 = pairs[i + 768];
            atomicAdd(&cnt[p0 & (BNODES - 1)], 1);
            atomicAdd(&cnt[p1 & (BNODES - 1)], 1);
            atomicAdd(&cnt[p2 & (BNODES - 1)], 1);
            atomicAdd(&cnt[p3 & (BNODES - 1)], 1);
        }
        for (; i < ee; i += 256) atomicAdd(&cnt[pairs[i] & (BNODES - 1)], 1);
    }
    __syncthreads();

    if (t < 64) {                      // wave 0: 32-wide shuffle scan
        const int lane = t;
        const int v = (lane < BNODES) ? cnt[lane] : 0;
        int xs = v;
#pragma unroll
        for (int off = 1; off < BNODES; off <<= 1) {
            int y = __shfl_up(xs, off);
            if (lane >= off) xs += y;
        }
        if (lane < BNODES) {
            const int excl = xs - v;
            cur[lane] = eb + excl;
            const int n = (b << BSHIFT) + lane;
            if (n <= N_NODES) nodeoff[n] = eb + excl;
            if (n < N_NODES)  dinv[n] = rsqrtf((float)(v + 1));
        }
    }
    __syncthreads();

    {
        int i = eb + t;
        for (; i + 768 < ee; i += 1024) {
            const unsigned p0 = pairs[i];
            const unsigned p1 = pairs[i + 256];
            const unsigned p2 = pairs[i + 512];
            const unsigned p3 = pairs[i + 768];
            int q;
            q = atomicAdd(&cur[p0 & (BNODES - 1)], 1); csr[q] = (unsigned short)(p0 >> 16);
            q = atomicAdd(&cur[p1 & (BNODES - 1)], 1); csr[q] = (unsigned short)(p1 >> 16);
            q = atomicAdd(&cur[p2 & (BNODES - 1)], 1); csr[q] = (unsigned short)(p2 >> 16);
            q = atomicAdd(&cur[p3 & (BNODES - 1)], 1); csr[q] = (unsigned short)(p3 >> 16);
        }
        for (; i < ee; i += 256) {
            const unsigned p = pairs[i];
            const int q = atomicAdd(&cur[p & (BNODES - 1)], 1);
            csr[q] = (unsigned short)(p >> 16);
        }
    }
}

// ---------------------------------------------------------------------------
// GEMM via f16 MFMA: h[n,:] = (half)((x[n,:] @ W) * dinv[n]).
// B-frags (all of W) in VGPRs once/wave; A-frags straight from global.
// MFMA 16x16x32_f16: A[m=lane&15][k=quad*8+j]; B[k][n=lane&15];
// C/D: row=quad*4+reg, col=lane&15 (m89-verified; validated R6, absmax 0.031).
// ---------------------------------------------------------------------------
__global__ __launch_bounds__(256) void k_gemm(const float* __restrict__ x,
                                              const float* __restrict__ W,
                                              const float* __restrict__ dinv,
                                              __half* __restrict__ h) {
    const int t = threadIdx.x;
    const int w = t >> 6;
    const int l = t & 63;
    const int q = l >> 4;
    const int m16 = l & 15;

    f16x8 bf[4][4];
#pragma unroll
    for (int kc = 0; kc < 4; ++kc)
#pragma unroll
        for (int ct = 0; ct < 4; ++ct) {
            const float* wp = W + (size_t)(kc * 32 + q * 8) * DIM_OUT + ct * 16 + m16;
            f16x8 v;
#pragma unroll
            for (int j = 0; j < 8; ++j) v[j] = (_Float16)wp[(size_t)j * DIM_OUT];
            bf[kc][ct] = v;
        }

    const int base = blockIdx.x * GROWS + w * 32;
#pragma unroll
    for (int rt = 0; rt < 2; ++rt) {
        const int m0 = base + rt * 16;
        int mrow = m0 + m16;
        if (mrow >= N_NODES) mrow = N_NODES - 1;   // clamp (stores guarded)

        f16x8 af[4];
#pragma unroll
        for (int kc = 0; kc < 4; ++kc) {
            const float4* xp = (const float4*)(x + (size_t)mrow * DIM_IN + kc * 32 + q * 8);
            const float4 p0 = xp[0], p1 = xp[1];
            f16x8 a;
            a[0] = (_Float16)p0.x; a[1] = (_Float16)p0.y;
            a[2] = (_Float16)p0.z; a[3] = (_Float16)p0.w;
            a[4] = (_Float16)p1.x; a[5] = (_Float16)p1.y;
            a[6] = (_Float16)p1.z; a[7] = (_Float16)p1.w;
            af[kc] = a;
        }

        f32x4 acc[4];
#pragma unroll
        for (int ct = 0; ct < 4; ++ct) acc[ct] = (f32x4){0.f, 0.f, 0.f, 0.f};
#pragma unroll
        for (int kc = 0; kc < 4; ++kc)
#pragma unroll
            for (int ct = 0; ct < 4; ++ct)
                acc[ct] = __builtin_amdgcn_mfma_f32_16x16x32_f16(af[kc], bf[kc][ct], acc[ct], 0, 0, 0);

#pragma unroll
        for (int reg = 0; reg < 4; ++reg) {
            const int r = m0 + q * 4 + reg;
            if (r < N_NODES) {
                const float d = dinv[r];
#pragma unroll
                for (int ct = 0; ct < 4; ++ct)
                    h[(size_t)r * DIM_OUT + ct * 16 + m16] = __float2half(acc[ct][reg] * d);
            }
        }
    }
}

// ---------------------------------------------------------------------------
// E: pure CSR gather + bias + log_softmax. QUARTER-wave per node: 16 lanes,
// each lane = 4 channels via one 8 B f16x4 load -> per-edge VMEM instruction
// count halves vs half-wave. 3125 blocks x 16 nodes.
// ---------------------------------------------------------------------------
__global__ __launch_bounds__(256) void kE_agg(const int* __restrict__ nodeoff,
                                              const unsigned short* __restrict__ csr,
                                              const __half* __restrict__ h,
                                              const float* __restrict__ bvec,
                                              float* __restrict__ out) {
    const int t = threadIdx.x;
    const int qw = t >> 4, sl = t & 15;      // quarter-wave id / sub-lane
    const int n = blockIdx.x * 16 + qw;      // 3125*16 = 50000 exactly
    const f16x4* __restrict__ h4 = (const f16x4*)h;   // [n*16 + sl]

    const int s0 = nodeoff[n], s1 = nodeoff[n + 1];

    const f16x4 hv = h4[n * 16 + sl];        // self-loop term
    float a0f = (float)hv[0], a1f = (float)hv[1], a2f = (float)hv[2], a3f = (float)hv[3];

    int i = s0;
    for (; i + 4 <= s1; i += 4) {
        const int c0 = csr[i + 0];
        const int c1 = csr[i + 1];
        const int c2 = csr[i + 2];
        const int c3 = csr[i + 3];
        const f16x4 v0 = h4[c0 * 16 + sl];
        const f16x4 v1 = h4[c1 * 16 + sl];
        const f16x4 v2 = h4[c2 * 16 + sl];
        const f16x4 v3 = h4[c3 * 16 + sl];
        a0f += (float)v0[0] + (float)v1[0] + (float)v2[0] + (float)v3[0];
        a1f += (float)v0[1] + (float)v1[1] + (float)v2[1] + (float)v3[1];
        a2f += (float)v0[2] + (float)v1[2] + (float)v2[2] + (float)v3[2];
        a3f += (float)v0[3] + (float)v1[3] + (float)v2[3] + (float)v3[3];
    }
    for (; i < s1; ++i) {
        const f16x4 v0 = h4[csr[i] * 16 + sl];
        a0f += (float)v0[0]; a1f += (float)v0[1]; a2f += (float)v0[2]; a3f += (float)v0[3];
    }

    const float4 bias = *(const float4*)&bvec[4 * sl];
    const float di = rsqrtf((float)(s1 - s0 + 1));
    float v0 = a0f * di + bias.x;
    float v1 = a1f * di + bias.y;
    float v2 = a2f * di + bias.z;
    float v3 = a3f * di + bias.w;

    float m = fmaxf(fmaxf(v0, v1), fmaxf(v2, v3));
#pragma unroll
    for (int off = 8; off > 0; off >>= 1) m = fmaxf(m, __shfl_xor(m, off));
    float s = __expf(v0 - m) + __expf(v1 - m) + __expf(v2 - m) + __expf(v3 - m);
#pragma unroll
    for (int off = 8; off > 0; off >>= 1) s += __shfl_xor(s, off);
    const float ls = __logf(s);

    float4 o;
    o.x = v0 - m - ls; o.y = v1 - m - ls; o.z = v2 - m - ls; o.w = v3 - m - ls;
    *(float4*)&out[(size_t)n * DIM_OUT + 4 * sl] = o;
}

// ---------------------------------------------------------------------------
extern "C" void kernel_launch(void* const* d_in, const int* in_sizes, int n_in,
                              void* d_out, int out_size, void* d_ws, size_t ws_size,
                              hipStream_t stream) {
    const float* x  = (const float*)d_in[0];
    const int*   ei = (const int*)d_in[1];   // [2, E]: row0 = src, row1 = dst
    const float* W  = (const float*)d_in[2];
    const float* b  = (const float*)d_in[3];
    float* out = (float*)d_out;

    // workspace layout (~14 MB of the 256 MB ws):
    char* ws = (char*)d_ws;
    __half*         h       = (__half*)ws;         ws += (size_t)N_NODES * DIM_OUT * sizeof(__half);
    float*          dinv    = (float*)ws;          ws += (size_t)N_NODES * sizeof(float);
    unsigned*       pairs   = (unsigned*)ws;       ws += (size_t)N_EDGES * sizeof(unsigned);
    unsigned short* csr     = (unsigned short*)ws; ws += (size_t)N_EDGES * sizeof(unsigned short);
    int*            nodeoff = (int*)ws;            ws += (size_t)(N_NODES + 1) * sizeof(int);
    ws = (char*)(((uintptr_t)ws + 15) & ~(uintptr_t)15);
    int*            M       = (int*)ws;            ws += (size_t)SORTB * NB * sizeof(int);
    int*            startsL = (int*)ws;            ws += (size_t)SORTB * NB * sizeof(int);
    int*            colsum  = (int*)ws;            ws += (size_t)NB * sizeof(int);
    int*            bstart  = (int*)ws;            ws += (size_t)(NB + 1) * sizeof(int);

    kA_hist   <<<SORTB, 256, 0, stream>>>(ei, M);
    kB_tile   <<<NB, 256, 0, stream>>>(M, startsL, colsum);
    kB_scan   <<<1, 1024, 0, stream>>>(colsum, bstart);
    kC_scatter<<<SORTB, 256, 0, stream>>>(ei, startsL, bstart, pairs);
    kSort     <<<NBK, 256, 0, stream>>>(pairs, bstart, csr, nodeoff, dinv);
    k_gemm    <<<(N_NODES + GROWS - 1) / GROWS, 256, 0, stream>>>(x, W, dinv, h);
    kE_agg    <<<N_NODES / 16, 256, 0, stream>>>(nodeoff, csr, h, b, out);
}

// Round 9
// 123.539 us; speedup vs baseline: 3.9238x; 1.0680x over previous
//
#include <hip/hip_runtime.h>
#include <hip/hip_fp16.h>
#include <cstdint>
#include <cstddef>

#define N_NODES 50000
#define N_EDGES 800000
#define DIM_IN  128
#define DIM_OUT 64

#define BSHIFT  6                                  // 64 nodes per bucket
#define BNODES  64
#define NB      1024                               // padded bucket count (pow2)
#define NBK     ((N_NODES + BNODES - 1) / BNODES)  // 782 buckets used
#define EB      4096                               // edges per tile
#define SORTB   ((N_EDGES + EB - 1) / EB)          // 196 tiles
#define NE4     (N_EDGES / 4)                      // 200000 int4 edge groups
#define CAPB    1280                               // slots/bucket (mean 781, sd 28: 18-sigma)
#define GROWS   128                                // gemm rows per block

typedef _Float16 f16x8 __attribute__((ext_vector_type(8)));
typedef _Float16 f16x4 __attribute__((ext_vector_type(4)));
typedef float    f32x4 __attribute__((ext_vector_type(4)));

// ---------------------------------------------------------------------------
// Zero the 1024 global bucket counters (ws is poisoned 0xAA before each call).
// ---------------------------------------------------------------------------
__global__ __launch_bounds__(256) void k_zero(int* __restrict__ gcnt) {
    const int i = blockIdx.x * 256 + threadIdx.x;
    if (i < NB) gcnt[i] = 0;
}

// ---------------------------------------------------------------------------
// F: fused front-end. Per tile: (1) LDS histogram over dst-buckets,
// (2) reserve a contiguous run in each bucket's padded region via ONE global
// atomic per (tile,bucket) — 200K total, not 800K per-edge, (3) scatter
// packed (src<<16)|dst with LDS cursors. Replaces kA/kB_tile/kB_scan/kC.
// ---------------------------------------------------------------------------
__global__ __launch_bounds__(256) void kF(const int* __restrict__ ei,
                                          int* __restrict__ gcnt,
                                          unsigned* __restrict__ pairs) {
    __shared__ int hcnt[NB];
    __shared__ int cur[NB];
    const int t = threadIdx.x, blk = blockIdx.x;
    for (int i = t; i < NB; i += 256) hcnt[i] = 0;
    __syncthreads();

    const int4* src4 = (const int4*)ei;
    const int4* dst4 = (const int4*)(ei + N_EDGES);
    const int g0 = blk * (EB / 4);

#pragma unroll
    for (int it = 0; it < EB / 1024; ++it) {          // pass 1: histogram
        const int g = g0 + it * 256 + t;
        if (g < NE4) {
            const int4 d = dst4[g];
            atomicAdd(&hcnt[d.x >> BSHIFT], 1);
            atomicAdd(&hcnt[d.y >> BSHIFT], 1);
            atomicAdd(&hcnt[d.z >> BSHIFT], 1);
            atomicAdd(&hcnt[d.w >> BSHIFT], 1);
        }
    }
    __syncthreads();

    for (int i = t; i < NB; i += 256) {               // reserve runs
        const int c = hcnt[i];
        const int base = c ? atomicAdd(&gcnt[i], c) : 0;
        cur[i] = i * CAPB + base;
    }
    __syncthreads();

#pragma unroll
    for (int it = 0; it < EB / 1024; ++it) {          // pass 2: scatter (L2-hot reread)
        const int g = g0 + it * 256 + t;
        if (g < NE4) {
            const int4 sv = src4[g];
            const int4 dv = dst4[g];
            int b, p;
            b = dv.x >> BSHIFT; p = atomicAdd(&cur[b], 1);
            if (p < b * CAPB + CAPB) pairs[p] = ((unsigned)sv.x << 16) | (unsigned)dv.x;
            b = dv.y >> BSHIFT; p = atomicAdd(&cur[b], 1);
            if (p < b * CAPB + CAPB) pairs[p] = ((unsigned)sv.y << 16) | (unsigned)dv.y;
            b = dv.z >> BSHIFT; p = atomicAdd(&cur[b], 1);
            if (p < b * CAPB + CAPB) pairs[p] = ((unsigned)sv.z << 16) | (unsigned)dv.z;
            b = dv.w >> BSHIFT; p = atomicAdd(&cur[b], 1);
            if (p < b * CAPB + CAPB) pairs[p] = ((unsigned)sv.w << 16) | (unsigned)dv.w;
        }
    }
}

// ---------------------------------------------------------------------------
// Sort: per bucket (64 nodes), node-granular counting sort into padded csr,
// emitting nodeoff2[n] = (start, deg) and dinv = rsqrt(deg+1).
// 4-deep unrolled passes keep independent loads in flight.
// ---------------------------------------------------------------------------
__global__ __launch_bounds__(256) void kSort(const unsigned* __restrict__ pairs,
                                             const int* __restrict__ gcnt,
                                             unsigned short* __restrict__ csr,
                                             int2* __restrict__ nodeoff2,
                                             float* __restrict__ dinv) {
    __shared__ int cnt[BNODES];
    __shared__ int cur[BNODES];
    const int b = blockIdx.x, t = threadIdx.x;
    const int eb = b * CAPB;
    const int count = min(gcnt[b], CAPB);             // clamp matches kF guard
    const int ee = eb + count;

    if (t < BNODES) cnt[t] = 0;
    __syncthreads();

    {
        int i = eb + t;
        for (; i + 768 < ee; i += 1024) {
            const unsigned p0 = pairs[i];
            const unsigned p1 = pairs[i + 256];
            const unsigned p2 = pairs[i + 512];
            const unsigned p3 = pairs[i + 768];
            atomicAdd(&cnt[p0 & (BNODES - 1)], 1);
            atomicAdd(&cnt[p1 & (BNODES - 1)], 1);
            atomicAdd(&cnt[p2 & (BNODES - 1)], 1);
            atomicAdd(&cnt[p3 & (BNODES - 1)], 1);
        }
        for (; i < ee; i += 256) atomicAdd(&cnt[pairs[i] & (BNODES - 1)], 1);
    }
    __syncthreads();

    if (t < 64) {                       // wave 0: 64-wide shuffle scan
        const int lane = t;
        const int v = cnt[lane];
        int xs = v;
#pragma unroll
        for (int off = 1; off < 64; off <<= 1) {
            int y = __shfl_up(xs, off);
            if (lane >= off) xs += y;
        }
        const int excl = xs - v;
        cur[lane] = eb + excl;
        const int n = (b << BSHIFT) + lane;
        if (n < N_NODES) {
            nodeoff2[n] = make_int2(eb + excl, v);
            dinv[n] = rsqrtf((float)(v + 1));
        }
    }
    __syncthreads();

    {
        int i = eb + t;
        for (; i + 768 < ee; i += 1024) {
            const unsigned p0 = pairs[i];
            const unsigned p1 = pairs[i + 256];
            const unsigned p2 = pairs[i + 512];
            const unsigned p3 = pairs[i + 768];
            int q;
            q = atomicAdd(&cur[p0 & (BNODES - 1)], 1); csr[q] = (unsigned short)(p0 >> 16);
            q = atomicAdd(&cur[p1 & (BNODES - 1)], 1); csr[q] = (unsigned short)(p1 >> 16);
            q = atomicAdd(&cur[p2 & (BNODES - 1)], 1); csr[q] = (unsigned short)(p2 >> 16);
            q = atomicAdd(&cur[p3 & (BNODES - 1)], 1); csr[q] = (unsigned short)(p3 >> 16);
        }
        for (; i < ee; i += 256) {
            const unsigned p = pairs[i];
            const int q = atomicAdd(&cur[p & (BNODES - 1)], 1);
            csr[q] = (unsigned short)(p >> 16);
        }
    }
}

// ---------------------------------------------------------------------------
// GEMM via f16 MFMA: h[n,:] = (half)((x[n,:] @ W) * dinv[n]).
// B-frags (all of W) in VGPRs once/wave; A-frags straight from global.
// MFMA 16x16x32_f16: A[m=lane&15][k=quad*8+j]; B[k][n=lane&15];
// C/D: row=quad*4+reg, col=lane&15 (m89-verified; validated R6-R8, absmax 0.031).
// ---------------------------------------------------------------------------
__global__ __launch_bounds__(256) void k_gemm(const float* __restrict__ x,
                                              const float* __restrict__ W,
                                              const float* __restrict__ dinv,
                                              __half* __restrict__ h) {
    const int t = threadIdx.x;
    const int w = t >> 6;
    const int l = t & 63;
    const int q = l >> 4;
    const int m16 = l & 15;

    f16x8 bf[4][4];
#pragma unroll
    for (int kc = 0; kc < 4; ++kc)
#pragma unroll
        for (int ct = 0; ct < 4; ++ct) {
            const float* wp = W + (size_t)(kc * 32 + q * 8) * DIM_OUT + ct * 16 + m16;
            f16x8 v;
#pragma unroll
            for (int j = 0; j < 8; ++j) v[j] = (_Float16)wp[(size_t)j * DIM_OUT];
            bf[kc][ct] = v;
        }

    const int base = blockIdx.x * GROWS + w * 32;
#pragma unroll
    for (int rt = 0; rt < 2; ++rt) {
        const int m0 = base + rt * 16;
        int mrow = m0 + m16;
        if (mrow >= N_NODES) mrow = N_NODES - 1;   // clamp (stores guarded)

        f16x8 af[4];
#pragma unroll
        for (int kc = 0; kc < 4; ++kc) {
            const float4* xp = (const float4*)(x + (size_t)mrow * DIM_IN + kc * 32 + q * 8);
            const float4 p0 = xp[0], p1 = xp[1];
            f16x8 a;
            a[0] = (_Float16)p0.x; a[1] = (_Float16)p0.y;
            a[2] = (_Float16)p0.z; a[3] = (_Float16)p0.w;
            a[4] = (_Float16)p1.x; a[5] = (_Float16)p1.y;
            a[6] = (_Float16)p1.z; a[7] = (_Float16)p1.w;
            af[kc] = a;
        }

        f32x4 acc[4];
#pragma unroll
        for (int ct = 0; ct < 4; ++ct) acc[ct] = (f32x4){0.f, 0.f, 0.f, 0.f};
#pragma unroll
        for (int kc = 0; kc < 4; ++kc)
#pragma unroll
            for (int ct = 0; ct < 4; ++ct)
                acc[ct] = __builtin_amdgcn_mfma_f32_16x16x32_f16(af[kc], bf[kc][ct], acc[ct], 0, 0, 0);

#pragma unroll
        for (int reg = 0; reg < 4; ++reg) {
            const int r = m0 + q * 4 + reg;
            if (r < N_NODES) {
                const float d = dinv[r];
#pragma unroll
                for (int ct = 0; ct < 4; ++ct)
                    h[(size_t)r * DIM_OUT + ct * 16 + m16] = __float2half(acc[ct][reg] * d);
            }
        }
    }
}

// ---------------------------------------------------------------------------
// E: pure CSR gather + bias + log_softmax. Quarter-wave per node: 16 lanes,
// lane = 4 channels via one 8 B f16x4 load. 3125 blocks x 16 nodes.
// ---------------------------------------------------------------------------
__global__ __launch_bounds__(256) void kE_agg(const int2* __restrict__ nodeoff2,
                                              const unsigned short* __restrict__ csr,
                                              const __half* __restrict__ h,
                                              const float* __restrict__ bvec,
                                              float* __restrict__ out) {
    const int t = threadIdx.x;
    const int qw = t >> 4, sl = t & 15;
    const int n = blockIdx.x * 16 + qw;      // 3125*16 = 50000 exactly
    const f16x4* __restrict__ h4 = (const f16x4*)h;

    const int2 off = nodeoff2[n];
    const int s0 = off.x, s1 = off.x + off.y;

    const f16x4 hv = h4[n * 16 + sl];        // self-loop term
    float a0f = (float)hv[0], a1f = (float)hv[1], a2f = (float)hv[2], a3f = (float)hv[3];

    int i = s0;
    for (; i + 4 <= s1; i += 4) {
        const int c0 = csr[i + 0];
        const int c1 = csr[i + 1];
        const int c2 = csr[i + 2];
        const int c3 = csr[i + 3];
        const f16x4 v0 = h4[c0 * 16 + sl];
        const f16x4 v1 = h4[c1 * 16 + sl];
        const f16x4 v2 = h4[c2 * 16 + sl];
        const f16x4 v3 = h4[c3 * 16 + sl];
        a0f += (float)v0[0] + (float)v1[0] + (float)v2[0] + (float)v3[0];
        a1f += (float)v0[1] + (float)v1[1] + (float)v2[1] + (float)v3[1];
        a2f += (float)v0[2] + (float)v1[2] + (float)v2[2] + (float)v3[2];
        a3f += (float)v0[3] + (float)v1[3] + (float)v2[3] + (float)v3[3];
    }
    for (; i < s1; ++i) {
        const f16x4 v0 = h4[csr[i] * 16 + sl];
        a0f += (float)v0[0]; a1f += (float)v0[1]; a2f += (float)v0[2]; a3f += (float)v0[3];
    }

    const float4 bias = *(const float4*)&bvec[4 * sl];
    const float di = rsqrtf((float)(off.y + 1));
    float v0 = a0f * di + bias.x;
    float v1 = a1f * di + bias.y;
    float v2 = a2f * di + bias.z;
    float v3 = a3f * di + bias.w;

    float m = fmaxf(fmaxf(v0, v1), fmaxf(v2, v3));
#pragma unroll
    for (int off2 = 8; off2 > 0; off2 >>= 1) m = fmaxf(m, __shfl_xor(m, off2));
    float s = __expf(v0 - m) + __expf(v1 - m) + __expf(v2 - m) + __expf(v3 - m);
#pragma unroll
    for (int off2 = 8; off2 > 0; off2 >>= 1) s += __shfl_xor(s, off2);
    const float ls = __logf(s);

    float4 o;
    o.x = v0 - m - ls; o.y = v1 - m - ls; o.z = v2 - m - ls; o.w = v3 - m - ls;
    *(float4*)&out[(size_t)n * DIM_OUT + 4 * sl] = o;
}

// ---------------------------------------------------------------------------
extern "C" void kernel_launch(void* const* d_in, const int* in_sizes, int n_in,
                              void* d_out, int out_size, void* d_ws, size_t ws_size,
                              hipStream_t stream) {
    const float* x  = (const float*)d_in[0];
    const int*   ei = (const int*)d_in[1];   // [2, E]: row0 = src, row1 = dst
    const float* W  = (const float*)d_in[2];
    const float* b  = (const float*)d_in[3];
    float* out = (float*)d_out;

    // workspace (~15 MB of the 256 MB ws):
    char* ws = (char*)d_ws;
    __half*         h        = (__half*)ws;         ws += (size_t)N_NODES * DIM_OUT * sizeof(__half);
    float*          dinv     = (float*)ws;          ws += (size_t)N_NODES * sizeof(float);
    unsigned*       pairs    = (unsigned*)ws;       ws += (size_t)NB * CAPB * sizeof(unsigned);
    unsigned short* csr      = (unsigned short*)ws; ws += (size_t)NB * CAPB * sizeof(unsigned short);
    int2*           nodeoff2 = (int2*)ws;           ws += (size_t)N_NODES * sizeof(int2);
    int*            gcnt     = (int*)ws;            ws += (size_t)NB * sizeof(int);

    k_zero<<<(NB + 255) / 256, 256, 0, stream>>>(gcnt);
    kF    <<<SORTB, 256, 0, stream>>>(ei, gcnt, pairs);
    kSort <<<NBK, 256, 0, stream>>>(pairs, gcnt, csr, nodeoff2, dinv);
    k_gemm<<<(N_NODES + GROWS - 1) / GROWS, 256, 0, stream>>>(x, W, dinv, h);
    kE_agg<<<N_NODES / 16, 256, 0, stream>>>(nodeoff2, csr, h, b, out);
}